// Round 5
// baseline (256.662 us; speedup 1.0000x reference)
//
#include <hip/hip_runtime.h>
#include <hip/hip_bf16.h>

// ProbAttention (Informer ProbSparse), b=4 h=8 L=4096 d=64, sample_k=n_top=41.
// I/O: q,k,v fp32; index int32; output fp32. kE uses bf16 MFMA internally.
//
// 4-dispatch pipeline (fused for overlap):
//  K1 = kC1 (V partial sums, 512 blocks) ∥ kA (sampled scores, 4096 blocks)
//  kB = per-bh exact top-41 (radix select + exact tail argmax)
//  K3 = kE (flash attn for top-41, 512 blocks, first) ∥ kD (mean broadcast, 2048)
//  kF = merge tile partials, scatter top rows (overwrites kD's rows)

#define NTOP 41
#define NPAD 48
#define CH 64
#define CAND_CAP 64

typedef __attribute__((ext_vector_type(8))) short bf16x8;
typedef __attribute__((ext_vector_type(4))) float f32x4;

__device__ __forceinline__ unsigned short f2bf(float f) {
    unsigned int x = __float_as_uint(f);
    unsigned int r = (x + 0x7FFFu + ((x >> 16) & 1u)) >> 16;  // RNE
    return (unsigned short)r;
}
__device__ __forceinline__ unsigned int pack2(float lo, float hi) {
    return ((unsigned int)f2bf(hi) << 16) | f2bf(lo);
}
__device__ __forceinline__ float dot8(const float4& qa, const float4& qb,
                                      const float4& ka, const float4& kb) {
    float p = 0.f;
    p = fmaf(qa.x, ka.x, p); p = fmaf(qa.y, ka.y, p);
    p = fmaf(qa.z, ka.z, p); p = fmaf(qa.w, ka.w, p);
    p = fmaf(qb.x, kb.x, p); p = fmaf(qb.y, kb.y, p);
    p = fmaf(qb.z, kb.z, p); p = fmaf(qb.w, kb.w, p);
    return p;
}
__device__ __forceinline__ float red8(float p) {
    p += __shfl_xor(p, 1);
    p += __shfl_xor(p, 2);
    p += __shfl_xor(p, 4);
    return p;
}

// ---------------- K1: kC1 (bid<512) + kA (bid>=512) --------------------------
// kA: 8 lanes/query, XCD swizzle (bh slice pinned to one XCD's L2),
//     8-deep explicit gather pipeline. kC1: V partial sums.
__global__ __launch_bounds__(256, 5) void K1_scores_vsum(const float* __restrict__ q,
                                                         const float* __restrict__ k,
                                                         const float* __restrict__ v,
                                                         const int* __restrict__ idxs,
                                                         float* __restrict__ m_out,
                                                         float* __restrict__ vpart) {
    __shared__ __align__(16) char smem[32 * 41 * 4 > 1024 ? 32 * 41 * 4 : 1024];
    int t = threadIdx.x;
    int bid = blockIdx.x;

    if (bid < 512) {  // ---- kC1: V partial sums ----
        float* red = (float*)smem;
        int bh = bid >> 4, chn = bid & 15;
        int d = t & 63, r = t >> 6;
        long long base = ((long long)bh << 12) + chn * 256;
        float acc = 0.f;
        for (int i = 0; i < 64; i++) acc += v[(base + i * 4 + r) * 64 + d];
        red[t] = acc;
        __syncthreads();
        if (r == 0)
            vpart[(bh * 16 + chn) * 64 + d] = red[d] + red[64 + d] + red[128 + d] + red[192 + d];
        return;
    }

    // ---- kA: sampled scores m = max - mean ----
    int* sidx = (int*)smem;
    int abid = bid - 512;
    int lane = t & 63, w = t >> 6;
    int g = lane >> 3, sl = lane & 7;
    int lb = ((abid & 7) << 9) + (abid >> 3);              // XCD swizzle
    long long qflat = (long long)lb * 32 + w * 8 + g;      // 0..131071
    int bh = (int)(qflat >> 12);
    int qi0 = (lb * 32) & 4095;
    for (int i = t; i < 32 * 41; i += 256)
        sidx[i] = idxs[(long long)qi0 * 41 + i] & 4095;
    const float4* q4 = (const float4*)q;  // 16 float4 per row
    const float4* k4 = (const float4*)k;
    float4 qa = q4[qflat * 16 + sl * 2];
    float4 qb = q4[qflat * 16 + sl * 2 + 1];
    long long kbase = ((long long)bh << 12) * 16;
    __syncthreads();
    const int* irow = sidx + (w * 8 + g) * 41;

    // prefetch remainder sample 40
    int k40 = irow[40];
    float4 ka40 = k4[kbase + (long long)k40 * 16 + sl * 2];
    float4 kb40 = k4[kbase + (long long)k40 * 16 + sl * 2 + 1];

    float maxv = -1e30f, sum = 0.f;
#pragma unroll
    for (int g8 = 0; g8 < 5; g8++) {
        int kis[8];
#pragma unroll
        for (int u = 0; u < 8; u++) kis[u] = irow[g8 * 8 + u];
        float4 ka[8], kb[8];
#pragma unroll
        for (int u = 0; u < 8; u++) {
            long long roff = kbase + (long long)kis[u] * 16 + sl * 2;
            ka[u] = k4[roff];
            kb[u] = k4[roff + 1];
        }
#pragma unroll
        for (int u = 0; u < 8; u++) {
            float p = red8(dot8(qa, qb, ka[u], kb[u]));
            maxv = fmaxf(maxv, p);
            sum += p;
        }
    }
    {
        float p = red8(dot8(qa, qb, ka40, kb40));
        maxv = fmaxf(maxv, p);
        sum += p;
    }
    if (sl == 0) m_out[qflat] = maxv - sum * (1.0f / 41.0f);
}

// ---------------- kB: exact top-41 per (b,h) via radix select ----------------
__global__ __launch_bounds__(256) void kB_topk(const float* __restrict__ m_in,
                                               int* __restrict__ topq) {
    __shared__ unsigned int uvals[4096];
    __shared__ unsigned int hist[256];
    __shared__ unsigned int scal[4];
    __shared__ int candIdx[CAND_CAP];
    __shared__ unsigned int candU[CAND_CAP];
    int bh = blockIdx.x, t = threadIdx.x;
    for (int i = t; i < 4096; i += 256) {
        unsigned int b = __float_as_uint(m_in[bh * 4096 + i]);
        uvals[i] = (b & 0x80000000u) ? ~b : (b | 0x80000000u);
    }
    hist[t] = 0;
    __syncthreads();
    for (int i = t; i < 4096; i += 256) atomicAdd(&hist[uvals[i] >> 24], 1u);
    __syncthreads();
    if (t == 0) {
        unsigned int cum = 0, b1 = 0, ca = 0;
        for (int j = 255; j >= 0; j--) {
            if (cum + hist[j] >= 41u) { b1 = (unsigned)j; ca = cum; break; }
            cum += hist[j];
        }
        scal[0] = b1; scal[1] = ca;
    }
    __syncthreads();
    unsigned int b1 = scal[0];
    hist[t] = 0;
    __syncthreads();
    for (int i = t; i < 4096; i += 256)
        if ((uvals[i] >> 24) == b1) atomicAdd(&hist[(uvals[i] >> 16) & 255u], 1u);
    __syncthreads();
    if (t == 0) {
        unsigned int cum = scal[1], b2 = 0;
        for (int j = 255; j >= 0; j--) {
            if (cum + hist[j] >= 41u) { b2 = (unsigned)j; break; }
            cum += hist[j];
        }
        scal[2] = (b1 << 24) | (b2 << 16);
        scal[3] = 0;
    }
    __syncthreads();
    unsigned int T = scal[2];
    for (int i = t; i < 4096; i += 256) {
        unsigned int u = uvals[i];
        if (u >= T) {
            unsigned int pos = atomicAdd(&scal[3], 1u);
            if (pos < CAND_CAP) { candIdx[pos] = i; candU[pos] = u; }
        }
    }
    __syncthreads();
    if (t < 64) {
        int n = (int)min(scal[3], (unsigned)CAND_CAP);
        unsigned int myU = (t < n) ? candU[t] : 0u;
        int myI = (t < n) ? candIdx[t] : 0x7fffffff;
        for (int it = 0; it < NTOP; it++) {
            unsigned int bu = myU;
            int bi = myI;
            for (int off = 32; off; off >>= 1) {
                unsigned int ou = __shfl_xor(bu, off);
                int oi = __shfl_xor(bi, off);
                if (ou > bu || (ou == bu && oi < bi)) { bu = ou; bi = oi; }
            }
            if (t == 0) topq[bh * NTOP + it] = bi;
            if (myI == bi) { myU = 0u; myI = 0x7fffffff; }
        }
    }
}

// ---------------- K3: kE (bid < tiles*32, first) + kD (rest) -----------------
// kE: flash attention over tl keys/tile; kD: finish v-mean + broadcast to out.
__global__ __launch_bounds__(256) void K3_attn_bcast(const float* __restrict__ q,
                                                     const float* __restrict__ k,
                                                     const float* __restrict__ v,
                                                     const int* __restrict__ topq,
                                                     const float* __restrict__ vpart,
                                                     float* __restrict__ part,
                                                     float* __restrict__ out,
                                                     int tiles, int tl) {
    __shared__ unsigned short qs[NPAD * 72];
    __shared__ unsigned short kb[CH * 72];
    __shared__ unsigned short vt[64 * 72];   // V transposed: vt[d][j]
    __shared__ unsigned short pb[NPAD * 72]; // P (exp scores) in bf16
    __shared__ float sp[NPAD * 65];          // raw scores fp32
    __shared__ float m_i[NPAD], l_i[NPAD], fac[NPAD];
    __shared__ __align__(16) float vm[64];

    const int t = threadIdx.x;
    const int bid = blockIdx.x;
    const int nE = tiles * 32;

    if (bid >= nE) {  // ---- kD: finish mean + broadcast ----
        int gb = bid - nE;
        int bh = gb >> 6;  // 64 blocks per bh
        if (t < 64) {
            float s = 0.f;
#pragma unroll
            for (int c = 0; c < 16; c++) s += vpart[(bh * 16 + c) * 64 + t];
            vm[t] = s * (1.0f / 4096.0f);
        }
        __syncthreads();
        long long g0 = (long long)gb * 1024 + t;  // float4 units
        float4* out4 = (float4*)out;
#pragma unroll
        for (int i = 0; i < 4; i++) {
            long long gg = g0 + i * 256;
            int d4 = (int)(gg & 15);
            out4[gg] = *(const float4*)(&vm[d4 * 4]);
        }
        return;
    }

    // ---- kE: flash attention ----
    // bid = xcd | (sub<<3) | (tile<<5): bh = xcd*4+sub -> bh's tiles share the
    // XCD whose L2 kA warmed with this bh's K slice.
    const int xcd = bid & 7, sub = (bid >> 3) & 3, tile = bid >> 5;
    const int bh = (xcd << 2) | sub;
    const int lane = t & 63, w = t >> 6;
    const int c = lane & 15, quad = lane >> 4;
    const long long bhbase = ((long long)bh) << 12;

    const float4* q4f = (const float4*)q;
    const float4* k4f = (const float4*)k;
    const float4* v4f = (const float4*)v;

    for (int i = t; i < NTOP * 16; i += 256) {
        int n = i >> 4, oc = i & 15;
        int row = topq[bh * NTOP + n];
        float4 val = q4f[(bhbase + row) * 16 + oc];
        uint2 pk;
        pk.x = pack2(val.x * 0.125f, val.y * 0.125f);
        pk.y = pack2(val.z * 0.125f, val.w * 0.125f);
        *(uint2*)(&qs[n * 72 + oc * 4]) = pk;
    }
    for (int i = t; i < 7 * 72; i += 256) {
        qs[NTOP * 72 + i] = 0;
        pb[NTOP * 72 + i] = 0;
    }
    if (t < NPAD) { m_i[t] = -1e30f; l_i[t] = 0.f; fac[t] = 0.f; }

    f32x4 oacc[3];
#pragma unroll
    for (int qt = 0; qt < 3; qt++) oacc[qt] = (f32x4){0.f, 0.f, 0.f, 0.f};

    const int l0 = tile * tl;
    const int nchunk = tl >> 6;
    for (int ch = 0; ch < nchunk; ch++) {
        const int lb = l0 + ch * CH;
        __syncthreads();
#pragma unroll
        for (int i = 0; i < 4; i++) {
            int idx = i * 256 + t;
            int j = idx >> 4, oc = idx & 15;
            float4 val = k4f[(bhbase + lb + j) * 16 + oc];
            uint2 pk;
            pk.x = pack2(val.x, val.y);
            pk.y = pack2(val.z, val.w);
            *(uint2*)(&kb[j * 72 + oc * 4]) = pk;
        }
        {
            int jp = t & 31, o = t >> 5;
            float4 a0 = v4f[(bhbase + lb + 2 * jp) * 16 + o * 2];
            float4 a1 = v4f[(bhbase + lb + 2 * jp) * 16 + o * 2 + 1];
            float4 b0 = v4f[(bhbase + lb + 2 * jp + 1) * 16 + o * 2];
            float4 b1 = v4f[(bhbase + lb + 2 * jp + 1) * 16 + o * 2 + 1];
            float av[8] = {a0.x, a0.y, a0.z, a0.w, a1.x, a1.y, a1.z, a1.w};
            float bv[8] = {b0.x, b0.y, b0.z, b0.w, b1.x, b1.y, b1.z, b1.w};
#pragma unroll
            for (int e = 0; e < 8; e++)
                *(unsigned int*)(&vt[(o * 8 + e) * 72 + 2 * jp]) = pack2(av[e], bv[e]);
        }
        __syncthreads();
        {
            const bf16x8 bk0 = *(const bf16x8*)(&kb[(w * 16 + c) * 72 + quad * 8]);
            const bf16x8 bk1 = *(const bf16x8*)(&kb[(w * 16 + c) * 72 + quad * 8 + 32]);
#pragma unroll
            for (int qt = 0; qt < 3; qt++) {
                const bf16x8 a0 = *(const bf16x8*)(&qs[(qt * 16 + c) * 72 + quad * 8]);
                const bf16x8 a1 = *(const bf16x8*)(&qs[(qt * 16 + c) * 72 + quad * 8 + 32]);
                f32x4 s4 = (f32x4){0.f, 0.f, 0.f, 0.f};
                s4 = __builtin_amdgcn_mfma_f32_16x16x32_bf16(a0, bk0, s4, 0, 0, 0);
                s4 = __builtin_amdgcn_mfma_f32_16x16x32_bf16(a1, bk1, s4, 0, 0, 0);
#pragma unroll
                for (int r = 0; r < 4; r++)
                    sp[(qt * 16 + quad * 4 + r) * 65 + w * 16 + c] = s4[r];
            }
        }
        __syncthreads();
        if (t < NTOP * 4) {
            int n = t >> 2, sub2 = t & 3;
            float rm = -1e30f;
#pragma unroll
            for (int j = 0; j < 16; j++) rm = fmaxf(rm, sp[n * 65 + sub2 * 16 + j]);
            rm = fmaxf(rm, __shfl_xor(rm, 1));
            rm = fmaxf(rm, __shfl_xor(rm, 2));
            float mo = m_i[n];
            float mn = fmaxf(mo, rm);
            float ssum = 0.f;
#pragma unroll
            for (int j = 0; j < 16; j += 2) {
                float e0 = __expf(sp[n * 65 + sub2 * 16 + j] - mn);
                float e1 = __expf(sp[n * 65 + sub2 * 16 + j + 1] - mn);
                ssum += e0 + e1;
                *(unsigned int*)(&pb[n * 72 + sub2 * 16 + j]) = pack2(e0, e1);
            }
            ssum += __shfl_xor(ssum, 1);
            ssum += __shfl_xor(ssum, 2);
            if (sub2 == 0) {
                float f = __expf(mo - mn);
                fac[n] = f;
                l_i[n] = l_i[n] * f + ssum;
                m_i[n] = mn;
            }
        }
        __syncthreads();
        {
            const bf16x8 bv0 = *(const bf16x8*)(&vt[(w * 16 + c) * 72 + quad * 8]);
            const bf16x8 bv1 = *(const bf16x8*)(&vt[(w * 16 + c) * 72 + quad * 8 + 32]);
#pragma unroll
            for (int qt = 0; qt < 3; qt++) {
                const bf16x8 a0 = *(const bf16x8*)(&pb[(qt * 16 + c) * 72 + quad * 8]);
                const bf16x8 a1 = *(const bf16x8*)(&pb[(qt * 16 + c) * 72 + quad * 8 + 32]);
                f32x4 o = oacc[qt];
                o.x *= fac[qt * 16 + quad * 4 + 0];
                o.y *= fac[qt * 16 + quad * 4 + 1];
                o.z *= fac[qt * 16 + quad * 4 + 2];
                o.w *= fac[qt * 16 + quad * 4 + 3];
                o = __builtin_amdgcn_mfma_f32_16x16x32_bf16(a0, bv0, o, 0, 0, 0);
                o = __builtin_amdgcn_mfma_f32_16x16x32_bf16(a1, bv1, o, 0, 0, 0);
                oacc[qt] = o;
            }
        }
    }
    __syncthreads();
    long long pbase = ((long long)(bh * tiles + tile)) * NTOP * 66;
    if (t < NTOP) {
        part[pbase + t * 66 + 0] = m_i[t];
        part[pbase + t * 66 + 1] = l_i[t];
    }
#pragma unroll
    for (int qt = 0; qt < 3; qt++) {
#pragma unroll
        for (int r = 0; r < 4; r++) {
            int n = qt * 16 + quad * 4 + r;
            if (n < NTOP) part[pbase + (long long)n * 66 + 2 + w * 16 + c] = oacc[qt][r];
        }
    }
}

// ---------------- kF: merge tile partials, scatter rows ----------------------
__global__ __launch_bounds__(256) void kF_combine(const float* __restrict__ part,
                                                  const int* __restrict__ topq,
                                                  float* __restrict__ out, int tiles) {
    int t = threadIdx.x;
    int bh = blockIdx.x;
    int n = blockIdx.y * 4 + (t >> 6);
    int d = t & 63;
    if (n >= NTOP) return;
    long long base = ((long long)(bh * tiles)) * NTOP * 66 + (long long)n * 66;
    const long long ts = (long long)NTOP * 66;
    float M = -1e30f;
    for (int tt = 0; tt < tiles; tt++) M = fmaxf(M, part[base + tt * ts]);
    float L = 0.f, acc = 0.f;
    for (int tt = 0; tt < tiles; tt++) {
        float mt = part[base + tt * ts];
        float wgt = __expf(mt - M);
        L += part[base + tt * ts + 1] * wgt;
        acc += part[base + tt * ts + 2 + d] * wgt;
    }
    int row = topq[bh * NTOP + n];
    out[(((long long)bh << 12) + row) * 64 + d] = acc / L;
}

// ---------------- launch -----------------------------------------------------
extern "C" void kernel_launch(void* const* d_in, const int* in_sizes, int n_in,
                              void* d_out, int out_size, void* d_ws, size_t ws_size,
                              hipStream_t stream) {
    const float* q = (const float*)d_in[0];
    const float* k = (const float*)d_in[1];
    const float* v = (const float*)d_in[2];
    const int* idxs = (const int*)d_in[3];
    float* out = (float*)d_out;

    char* ws = (char*)d_ws;
    float* ws_m = (float*)ws;                 // 131072 f  @ 0
    int* ws_topq = (int*)(ws + 524288);       // 1312 i
    float* ws_vpart = (float*)(ws + 532480);  // 32768 f
    float* ws_part = (float*)(ws + 671744);   // tiles*32*41*66 f

    size_t need16 = 671744ull + 16ull * 32 * NTOP * 66 * 4;
    int tiles = (ws_size >= need16) ? 16 : 8;
    int tl = 4096 / tiles;

    K1_scores_vsum<<<512 + 4096, 256, 0, stream>>>(q, k, v, idxs, ws_m, ws_vpart);
    kB_topk<<<32, 256, 0, stream>>>(ws_m, ws_topq);
    K3_attn_bcast<<<tiles * 32 + 2048, 256, 0, stream>>>(q, k, v, ws_topq, ws_vpart,
                                                         ws_part, out, tiles, tl);
    kF_combine<<<dim3(32, 11), 256, 0, stream>>>(ws_part, ws_topq, out, tiles);
}